// Round 6
// baseline (141.320 us; speedup 1.0000x reference)
//
#include <hip/hip_runtime.h>
#include <math.h>

namespace {
constexpr int kB = 2;
constexpr int kT = 4096;
constexpr int kD = 512;
constexpr int kH = 64;
constexpr int kRows = kB * kT;
constexpr int kRB = 16;   // rows per qkv block
constexpr int TQ = 16;    // queries per attn block
constexpr int NCH = 5;    // K/V chunks of 64 covering [t0-256, t0+63]
constexpr int CHS = 64;   // chunk size
constexpr int KVPAD = 68; // LDS row pad (f32 words)
}

// ---------------------------------------------------------------------------
// Kernel A: Q/K/V projection, split-D.
// 6 waves/block: wave (m, half) computes matrix m over d in [256*half, +256)
// for 16 rows. 16-accumulator register block per wave (ILP proven in R2),
// but half the latency chain and 2x the waves/CU vs R2 (3 waves/SIMD).
// Halves combined via LDS.
// ---------------------------------------------------------------------------
__global__ __launch_bounds__(384) void qkv_proj(const float* __restrict__ X,
                                                const float* __restrict__ Wq,
                                                const float* __restrict__ Wk,
                                                const float* __restrict__ Wv,
                                                float* __restrict__ Qo,
                                                float* __restrict__ Ko,
                                                float* __restrict__ Vo) {
  __shared__ float part[3][kRB][kH];
  const int tid = threadIdx.x;
  const int wv = tid >> 6;   // 0..5
  const int m = wv % 3;      // 0=Q, 1=K, 2=V
  const int half = wv / 3;   // 0 or 1
  const int h = tid & 63;
  const int row0 = blockIdx.x * kRB;
  const int d0 = half * (kD / 2);

  const float* __restrict__ Wbase = (m == 0) ? Wq : (m == 1) ? Wk : Wv;
  const float* __restrict__ Wp = Wbase + (size_t)d0 * kH;
  const float* __restrict__ xb = X + (size_t)row0 * kD + d0;

  float acc[kRB];
#pragma unroll
  for (int r = 0; r < kRB; ++r) acc[r] = 0.f;

  for (int d = 0; d < kD / 2; d += 4) {
    const float w0 = Wp[(d + 0) * kH + h];
    const float w1 = Wp[(d + 1) * kH + h];
    const float w2 = Wp[(d + 2) * kH + h];
    const float w3 = Wp[(d + 3) * kH + h];
#pragma unroll
    for (int r = 0; r < kRB; ++r) {
      const float4 x = *reinterpret_cast<const float4*>(xb + (size_t)r * kD + d);
      acc[r] = fmaf(x.w, w3, fmaf(x.z, w2, fmaf(x.y, w1, fmaf(x.x, w0, acc[r]))));
    }
  }

  if (half == 1) {
#pragma unroll
    for (int r = 0; r < kRB; ++r) part[m][r][h] = acc[r];
  }
  __syncthreads();
  if (half == 0) {
    float* __restrict__ out = (m == 0) ? Qo : (m == 1) ? Ko : Vo;
#pragma unroll
    for (int r = 0; r < kRB; ++r)
      out[(size_t)(row0 + r) * kH + h] = acc[r] + part[m][r][h];
  }
}

// ---------------------------------------------------------------------------
// Kernel B: sliding-window attention, 16 queries per block, LDS-staged K/V.
// (unchanged from R3 — ~15-18 us)
// ---------------------------------------------------------------------------
__global__ __launch_bounds__(256) void swin_attn(const float* __restrict__ Q,
                                                 const float* __restrict__ K,
                                                 const float* __restrict__ V,
                                                 float* __restrict__ O) {
  __shared__ float Qs[TQ][KVPAD];
  __shared__ float Sm[TQ][NCH * CHS];
  __shared__ float KV[CHS][KVPAD];

  const int tid = threadIdx.x;
  const int row0 = blockIdx.x * TQ;
  const int t0 = row0 & (kT - 1);
  const int b = row0 >> 12;
  const float* __restrict__ Kb = K + (size_t)b * kT * kH;
  const float* __restrict__ Vb = V + (size_t)b * kT * kH;

  {
    const int r = tid >> 4;
    const int h4 = (tid & 15) * 4;
    *reinterpret_cast<float4*>(&Qs[r][h4]) =
        *reinterpret_cast<const float4*>(&Q[(size_t)(row0 + r) * kH + h4]);
  }

  const int w = tid >> 6;
  const int lane = tid & 63;
  const int i0 = 4 * w;
  const int tmin = t0 + i0;
  const int tmax = t0 + i0 + 3;

  // ---- Phase A: scores ----
  for (int c = 0; c < NCH; ++c) {
    const int p0 = t0 - 256 + c * CHS;
    __syncthreads();
    for (int f = tid; f < CHS * kH / 4; f += 256) {
      const int r = f >> 4;
      const int h4 = (f & 15) * 4;
      const int p = p0 + r;
      float4 v = make_float4(0.f, 0.f, 0.f, 0.f);
      if (p >= 0 && p < kT)
        v = *reinterpret_cast<const float4*>(&Kb[(size_t)p * kH + h4]);
      *reinterpret_cast<float4*>(&KV[r][h4]) = v;
    }
    __syncthreads();

    const int lo = max(0, max(0, tmin - 255) - p0);
    const int hi = min(CHS - 1, tmax - p0);
    if (lo <= hi && lane >= lo && lane <= hi) {
      float s0 = 0.f, s1 = 0.f, s2 = 0.f, s3 = 0.f;
#pragma unroll
      for (int h0 = 0; h0 < kH; h0 += 4) {
        const float4 kv4 = *reinterpret_cast<const float4*>(&KV[lane][h0]);
        const float4 q0 = *reinterpret_cast<const float4*>(&Qs[i0 + 0][h0]);
        const float4 q1 = *reinterpret_cast<const float4*>(&Qs[i0 + 1][h0]);
        const float4 q2 = *reinterpret_cast<const float4*>(&Qs[i0 + 2][h0]);
        const float4 q3 = *reinterpret_cast<const float4*>(&Qs[i0 + 3][h0]);
        s0 = fmaf(kv4.w, q0.w, fmaf(kv4.z, q0.z, fmaf(kv4.y, q0.y, fmaf(kv4.x, q0.x, s0))));
        s1 = fmaf(kv4.w, q1.w, fmaf(kv4.z, q1.z, fmaf(kv4.y, q1.y, fmaf(kv4.x, q1.x, s1))));
        s2 = fmaf(kv4.w, q2.w, fmaf(kv4.z, q2.z, fmaf(kv4.y, q2.y, fmaf(kv4.x, q2.x, s2))));
        s3 = fmaf(kv4.w, q3.w, fmaf(kv4.z, q3.z, fmaf(kv4.y, q3.y, fmaf(kv4.x, q3.x, s3))));
      }
      const int jg = c * CHS + lane;
      Sm[i0 + 0][jg] = s0 * 0.125f;
      Sm[i0 + 1][jg] = s1 * 0.125f;
      Sm[i0 + 2][jg] = s2 * 0.125f;
      Sm[i0 + 3][jg] = s3 * 0.125f;
    }
  }
  __syncthreads();

  // ---- softmax: 16 lanes per query ----
  {
    const int i = tid >> 4;
    const int l = tid & 15;
    const int t = t0 + i;
    float sv[20];
    float mx = -INFINITY;
#pragma unroll
    for (int k2 = 0; k2 < 20; ++k2) {
      const int jg = l + 16 * k2;
      const int p = t0 - 256 + jg;
      const int jref = p - t + 255;
      const bool valid = (p >= 0) && (jref >= 0) && (jref <= 255) && (jref <= t);
      sv[k2] = valid ? Sm[i][jg] : -INFINITY;
      mx = fmaxf(mx, sv[k2]);
    }
#pragma unroll
    for (int off = 1; off < 16; off <<= 1) mx = fmaxf(mx, __shfl_xor(mx, off));
    const int n0 = (t < 255) ? min(t + 1, 255 - t) : 0;
    if (n0 > 0) mx = fmaxf(mx, 0.f);

    float sum = 0.f;
    float ev[20];
#pragma unroll
    for (int k2 = 0; k2 < 20; ++k2) {
      ev[k2] = (sv[k2] > -INFINITY) ? __expf(sv[k2] - mx) : 0.f;
      sum += ev[k2];
    }
#pragma unroll
    for (int off = 1; off < 16; off <<= 1) sum += __shfl_xor(sum, off);
    sum += (float)n0 * __expf(-mx);
    const float inv = 1.f / sum;
#pragma unroll
    for (int k2 = 0; k2 < 20; ++k2) Sm[i][l + 16 * k2] = ev[k2] * inv;
  }

  // ---- Phase B: PV ----
  float a0 = 0.f, a1 = 0.f, a2 = 0.f, a3 = 0.f;
  const int h = lane;
  for (int c = 0; c < NCH; ++c) {
    const int p0 = t0 - 256 + c * CHS;
    __syncthreads();
    for (int f = tid; f < CHS * kH / 4; f += 256) {
      const int r = f >> 4;
      const int h4 = (f & 15) * 4;
      const int p = p0 + r;
      float4 v = make_float4(0.f, 0.f, 0.f, 0.f);
      if (p >= 0 && p < kT)
        v = *reinterpret_cast<const float4*>(&Vb[(size_t)p * kH + h4]);
      *reinterpret_cast<float4*>(&KV[r][h4]) = v;
    }
    __syncthreads();

    const int lo = max(0, max(0, tmin - 255) - p0);
    const int hi = min(CHS - 1, tmax - p0);
    for (int q = lo; q <= hi; ++q) {
      const int jg = c * CHS + q;
      const float pv0 = Sm[i0 + 0][jg];
      const float pv1 = Sm[i0 + 1][jg];
      const float pv2 = Sm[i0 + 2][jg];
      const float pv3 = Sm[i0 + 3][jg];
      const float vv = KV[q][h];
      a0 = fmaf(pv0, vv, a0);
      a1 = fmaf(pv1, vv, a1);
      a2 = fmaf(pv2, vv, a2);
      a3 = fmaf(pv3, vv, a3);
    }
  }

  O[(size_t)(row0 + i0 + 0) * kH + h] = a0;
  O[(size_t)(row0 + i0 + 1) * kH + h] = a1;
  O[(size_t)(row0 + i0 + 2) * kH + h] = a2;
  O[(size_t)(row0 + i0 + 3) * kH + h] = a3;
}

// ---------------------------------------------------------------------------
extern "C" void kernel_launch(void* const* d_in, const int* in_sizes, int n_in,
                              void* d_out, int out_size, void* d_ws, size_t ws_size,
                              hipStream_t stream) {
  const float* X  = (const float*)d_in[0];
  const float* Wq = (const float*)d_in[1];
  const float* Wk = (const float*)d_in[2];
  const float* Wv = (const float*)d_in[3];
  float* Qo = (float*)d_ws;                 // [B*T][H]
  float* Ko = Qo + (size_t)kRows * kH;      // [B*T][H]
  float* Vo = Ko + (size_t)kRows * kH;      // [B*T][H]
  float* O = (float*)d_out;

  qkv_proj<<<kRows / kRB, 384, 0, stream>>>(X, Wq, Wk, Wv, Qo, Ko, Vo);
  swin_attn<<<kRows / TQ, 256, 0, stream>>>(Qo, Ko, Vo, O);
}